// Round 1
// baseline (623.790 us; speedup 1.0000x reference)
//
#include <hip/hip_runtime.h>
#include <hip/hip_bf16.h>
#include <cstdint>

typedef unsigned short u16;
typedef __bf16 bf16x8 __attribute__((ext_vector_type(8)));
typedef float f32x4 __attribute__((ext_vector_type(4)));

#define AS1 __attribute__((address_space(1)))
#define AS3 __attribute__((address_space(3)))

// ---------- exact MX quant-dequant helpers ----------

// Exact round-to-nearest-even onto the e4m3fn grid for y in [-448, 448].
// All steps are exact pow2 scalings + RNE rint -> bit-exact emulation.
__device__ __forceinline__ float e4m3_rne(float y) {
    float ay = fabsf(y);
    if (ay == 0.0f) return 0.0f;
    int e = ilogbf(ay);            // floor(log2|y|), exact incl. subnormals
    if (e < -6) e = -6;            // e4m3 subnormal cutoff (min quantum 2^-9)
    float r = rintf(ldexpf(y, 3 - e));   // RNE to integer, |r| <= 16
    return ldexpf(r, e - 3);
}

// scale = exp2(clip(floor(log2(amax)) - 8, -127, 127)), amax==0 -> amax:=1
__device__ __forceinline__ float block_scale(float amax) {
    float safe = (amax == 0.0f) ? 1.0f : amax;
    int se = ilogbf(safe) - 8;
    se = se < -127 ? -127 : (se > 127 ? 127 : se);
    return ldexpf(1.0f, se);
}

__device__ __forceinline__ float qdq_one(float v, float scale) {
    float y = v / scale;                       // exact (pow2 divisor)
    y = fminf(fmaxf(y, -448.0f), 448.0f);
    return e4m3_rne(y) * scale;                // exact pow2 mul; <=4 mantissa bits
}

__device__ __forceinline__ u16 bf16_bits(float v) {
    // value is exactly bf16-representable (<=4-bit mantissa): truncate
    return (u16)(__float_as_uint(v) >> 16);
}

// ---------- kernel 1: row-major qdq fp32 -> bf16 (blocks = 32 consecutive) ----------
// one thread = 4 elements (float4); 8 consecutive lanes share one 32-block
__global__ void qdq_rows(const float* __restrict__ in, u16* __restrict__ out) {
    size_t t = (size_t)blockIdx.x * 256 + threadIdx.x;
    float4 v = ((const float4*)in)[t];
    float a = fmaxf(fmaxf(fabsf(v.x), fabsf(v.y)), fmaxf(fabsf(v.z), fabsf(v.w)));
    a = fmaxf(a, __shfl_xor(a, 1));
    a = fmaxf(a, __shfl_xor(a, 2));
    a = fmaxf(a, __shfl_xor(a, 4));
    float s = block_scale(a);
    float q0 = qdq_one(v.x, s), q1 = qdq_one(v.y, s);
    float q2 = qdq_one(v.z, s), q3 = qdq_one(v.w, s);
    unsigned lo = (__float_as_uint(q0) >> 16) | (__float_as_uint(q1) & 0xffff0000u);
    unsigned hi = (__float_as_uint(q2) >> 16) | (__float_as_uint(q3) & 0xffff0000u);
    ((uint2*)out)[t] = make_uint2(lo, hi);
}

// ---------- kernel 2: qdq + transpose fp32 [R][C] -> bf16 [C][R] ----------
// blocks of 32 along C (input last dim). 64x64 tile through LDS.
__global__ void qdq_transpose(const float* __restrict__ in, u16* __restrict__ out,
                              int R, int C) {
    __shared__ u16 tile[64][68];   // +4 pad keeps 8B alignment for phase-2 reads
    int c0 = blockIdx.x * 64, r0 = blockIdx.y * 64;
    int t = threadIdx.x;
    #pragma unroll
    for (int p = 0; p < 4; ++p) {
        int lin = p * 256 + t;
        int row = lin >> 4;          // 16 float4 per 64-col row
        int c4  = lin & 15;
        float4 v = *(const float4*)(in + (size_t)(r0 + row) * C + c0 + c4 * 4);
        float a = fmaxf(fmaxf(fabsf(v.x), fabsf(v.y)), fmaxf(fabsf(v.z), fabsf(v.w)));
        a = fmaxf(a, __shfl_xor(a, 1));
        a = fmaxf(a, __shfl_xor(a, 2));
        a = fmaxf(a, __shfl_xor(a, 4));
        float s = block_scale(a);
        tile[c4 * 4 + 0][row] = bf16_bits(qdq_one(v.x, s));
        tile[c4 * 4 + 1][row] = bf16_bits(qdq_one(v.y, s));
        tile[c4 * 4 + 2][row] = bf16_bits(qdq_one(v.z, s));
        tile[c4 * 4 + 3][row] = bf16_bits(qdq_one(v.w, s));
    }
    __syncthreads();
    #pragma unroll
    for (int p = 0; p < 4; ++p) {
        int lin = p * 256 + t;
        int n  = lin >> 4;
        int k4 = lin & 15;
        unsigned lo = tile[n][k4 * 4 + 0] | ((unsigned)tile[n][k4 * 4 + 1] << 16);
        unsigned hi = tile[n][k4 * 4 + 2] | ((unsigned)tile[n][k4 * 4 + 3] << 16);
        *(uint2*)(out + (size_t)(c0 + n) * R + r0 + k4 * 4) = make_uint2(lo, hi);
    }
}

// ---------- kernel 3: bf16 GEMM, C = A * B  with B stored transposed [N][K] ----------
// 128x128 tile, BK=32, 4 waves as 2x2 of 64x64, 16x16x32 bf16 MFMA.
__global__ __launch_bounds__(256) void gemm_bt(const u16* __restrict__ A,
                                               const u16* __restrict__ B,
                                               float* __restrict__ C) {
    const int K = 4096, N = 4096;
    __shared__ __align__(16) u16 As[128 * 32];
    __shared__ __align__(16) u16 Bs[128 * 32];
    int t = threadIdx.x;
    int m0 = blockIdx.y * 128, n0 = blockIdx.x * 128;
    int w = t >> 6, lane = t & 63;
    int wm = (w >> 1) * 64, wc = (w & 1) * 64;
    int lcol = lane & 15, lq = lane >> 4;

    f32x4 acc[4][4];
    #pragma unroll
    for (int r = 0; r < 4; ++r)
        #pragma unroll
        for (int c = 0; c < 4; ++c) acc[r][c] = (f32x4){0.f, 0.f, 0.f, 0.f};

    // lane-contiguous staging map: 16B per lane per issue, 2 issues per operand
    int eo0 = t * 8;            // bf16 element offset within the 128x32 tile
    int eo1 = 2048 + t * 8;
    int ar0 = eo0 >> 5, ac0 = eo0 & 31;
    int ar1 = eo1 >> 5, ac1 = eo1 & 31;

    const u16* Ab = A + (size_t)m0 * K;
    const u16* Bb = B + (size_t)n0 * K;

    for (int k0 = 0; k0 < K; k0 += 32) {
        __builtin_amdgcn_global_load_lds((const AS1 unsigned*)(Ab + (size_t)ar0 * K + k0 + ac0),
                                         (AS3 unsigned*)&As[eo0], 16, 0, 0);
        __builtin_amdgcn_global_load_lds((const AS1 unsigned*)(Ab + (size_t)ar1 * K + k0 + ac1),
                                         (AS3 unsigned*)&As[eo1], 16, 0, 0);
        __builtin_amdgcn_global_load_lds((const AS1 unsigned*)(Bb + (size_t)ar0 * K + k0 + ac0),
                                         (AS3 unsigned*)&Bs[eo0], 16, 0, 0);
        __builtin_amdgcn_global_load_lds((const AS1 unsigned*)(Bb + (size_t)ar1 * K + k0 + ac1),
                                         (AS3 unsigned*)&Bs[eo1], 16, 0, 0);
        __syncthreads();

        bf16x8 af[4], bfv[4];
        #pragma unroll
        for (int r = 0; r < 4; ++r)
            af[r] = *(const bf16x8*)&As[(wm + r * 16 + lcol) * 32 + lq * 8];
        #pragma unroll
        for (int c = 0; c < 4; ++c)
            bfv[c] = *(const bf16x8*)&Bs[(wc + c * 16 + lcol) * 32 + lq * 8];

        #pragma unroll
        for (int r = 0; r < 4; ++r)
            #pragma unroll
            for (int c = 0; c < 4; ++c)
                acc[r][c] = __builtin_amdgcn_mfma_f32_16x16x32_bf16(af[r], bfv[c], acc[r][c], 0, 0, 0);
        __syncthreads();
    }

    // epilogue: C/D layout col = lane&15, row = (lane>>4)*4 + i
    #pragma unroll
    for (int r = 0; r < 4; ++r) {
        int gr = m0 + wm + r * 16 + lq * 4;
        #pragma unroll
        for (int c = 0; c < 4; ++c) {
            int gc = n0 + wc + c * 16 + lcol;
            #pragma unroll
            for (int i = 0; i < 4; ++i)
                C[(size_t)(gr + i) * N + gc] = acc[r][c][i];
        }
    }
}

// ---------- launch ----------
extern "C" void kernel_launch(void* const* d_in, const int* in_sizes, int n_in,
                              void* d_out, int out_size, void* d_ws, size_t ws_size,
                              hipStream_t stream) {
    const float* x  = (const float*)d_in[0];   // [4096, 4096]
    const float* m1 = (const float*)d_in[1];   // [4096, 4096]
    const float* m2 = (const float*)d_in[2];   // [4096, 4096]
    float* out = (float*)d_out;                // [4096, 4096] fp32

    const int M = 4096, K = 4096, N = 4096;
    const size_t MB = 1024 * 1024;
    char* ws = (char*)d_ws;
    u16*  xq   = (u16*)(ws + 0 * MB);    // 32 MB   qdq(x) bf16 [M][K]
    u16*  m1qT = (u16*)(ws + 32 * MB);   // 32 MB   qdq(mat1)^T bf16 [K][K]
    u16*  m2qT = (u16*)(ws + 64 * MB);   // 32 MB   qdq(mat2)^T bf16 [N][K]
    float* xh  = (float*)(ws + 96 * MB); // 64 MB   x_high fp32 [M][K]
    u16*  xrq  = (u16*)(ws + 0 * MB);    // reuse xq region (dead after GEMM1)

    dim3 b(256);
    qdq_rows<<<dim3((M * K) / 1024), b, 0, stream>>>(x, xq);
    qdq_transpose<<<dim3(K / 64, K / 64), b, 0, stream>>>(m1, m1qT, K, K);
    qdq_transpose<<<dim3(N / 64, K / 64), b, 0, stream>>>(m2, m2qT, K, N);
    gemm_bt<<<dim3(N / 128, M / 128), b, 0, stream>>>(xq, m1qT, xh);
    qdq_rows<<<dim3((M * K) / 1024), b, 0, stream>>>(xh, xrq);
    gemm_bt<<<dim3(N / 128, M / 128), b, 0, stream>>>(xrq, m2qT, out);
}

// Round 2
// 600.362 us; speedup vs baseline: 1.0390x; 1.0390x over previous
//
#include <hip/hip_runtime.h>
#include <hip/hip_bf16.h>
#include <cstdint>

typedef unsigned short u16;
typedef __bf16 bf16x8 __attribute__((ext_vector_type(8)));
typedef float f32x4 __attribute__((ext_vector_type(4)));
typedef float f32x2 __attribute__((ext_vector_type(2)));

#define AS1 __attribute__((address_space(1)))
#define AS3 __attribute__((address_space(3)))

// ---------- exact MX quant-dequant helpers (HW fp8 path) ----------

// floor(log2(x)) for x > 0, exact incl. subnormals, pure bit ops
__device__ __forceinline__ int floor_log2(float x) {
    unsigned b = __float_as_uint(x);
    if (b < 0x00800000u) {                       // subnormal (rare)
        b = __float_as_uint(x * 16777216.0f);    // * 2^24 exact
        return (int)(b >> 23) - 151;             // -127 - 24
    }
    return (int)(b >> 23) - 127;
}

// 2^e for e in [-149, 127]
__device__ __forceinline__ float exp2i(int e) {
    if (e >= -126) return __uint_as_float((unsigned)(e + 127) << 23);
    return __uint_as_float(0x00400000u >> (-127 - e));
}

// shared_exp = clip(floor(log2(amax)) - 8, -127, 127), amax==0 -> amax:=1
__device__ __forceinline__ int shared_exp(float amax) {
    float safe = (amax == 0.0f) ? 1.0f : amax;
    int se = floor_log2(safe) - 8;
    return se < -127 ? -127 : (se > 127 ? 127 : se);
}

// qdq two values sharing one scale; exact e4m3fn RNE via HW cvt
__device__ __forceinline__ void qdq2(float v0, float v1, float inv, float scale,
                                     float& o0, float& o1) {
    float y0 = fminf(fmaxf(v0 * inv, -448.0f), 448.0f);
    float y1 = fminf(fmaxf(v1 * inv, -448.0f), 448.0f);
    int pk = __builtin_amdgcn_cvt_pk_fp8_f32(y0, y1, 0, false);
    f32x2 f = __builtin_amdgcn_cvt_pk_f32_fp8(pk, false);
    o0 = f.x * scale;
    o1 = f.y * scale;
}

// pack two exactly-bf16-representable floats into u16x2 (truncate)
__device__ __forceinline__ unsigned pack_bf16(float a, float b) {
    return (__float_as_uint(a) >> 16) | (__float_as_uint(b) & 0xffff0000u);
}

// ---------- kernel 1: row-major qdq fp32 -> bf16 (blocks = 32 consecutive) ----------
// one thread = 8 elements; 4 consecutive lanes share one 32-block
__global__ void qdq_rows(const float* __restrict__ in, u16* __restrict__ out) {
    size_t t = (size_t)blockIdx.x * 256 + threadIdx.x;
    float4 v0 = ((const float4*)in)[t * 2];
    float4 v1 = ((const float4*)in)[t * 2 + 1];
    float a = fmaxf(fmaxf(fabsf(v0.x), fabsf(v0.y)), fmaxf(fabsf(v0.z), fabsf(v0.w)));
    a = fmaxf(a, fmaxf(fmaxf(fabsf(v1.x), fabsf(v1.y)), fmaxf(fabsf(v1.z), fabsf(v1.w))));
    a = fmaxf(a, __shfl_xor(a, 1));
    a = fmaxf(a, __shfl_xor(a, 2));
    int se = shared_exp(a);
    float s = exp2i(se), inv = exp2i(-se);
    float q0, q1, q2, q3, q4, q5, q6, q7;
    qdq2(v0.x, v0.y, inv, s, q0, q1);
    qdq2(v0.z, v0.w, inv, s, q2, q3);
    qdq2(v1.x, v1.y, inv, s, q4, q5);
    qdq2(v1.z, v1.w, inv, s, q6, q7);
    uint4 o;
    o.x = pack_bf16(q0, q1);
    o.y = pack_bf16(q2, q3);
    o.z = pack_bf16(q4, q5);
    o.w = pack_bf16(q6, q7);
    ((uint4*)out)[t] = o;
}

// ---------- kernel 2: qdq + transpose fp32 [R][C] -> bf16 [C][R] ----------
// blocks of 32 along C (input last dim). 64x64 tile through LDS.
__global__ void qdq_transpose(const float* __restrict__ in, u16* __restrict__ out,
                              int R, int C) {
    __shared__ u16 tile[64][68];
    int c0 = blockIdx.x * 64, r0 = blockIdx.y * 64;
    int t = threadIdx.x;
    #pragma unroll
    for (int p = 0; p < 4; ++p) {
        int lin = p * 256 + t;
        int row = lin >> 4;          // 16 float4 per 64-col row
        int c4  = lin & 15;
        float4 v = *(const float4*)(in + (size_t)(r0 + row) * C + c0 + c4 * 4);
        float a = fmaxf(fmaxf(fabsf(v.x), fabsf(v.y)), fmaxf(fabsf(v.z), fabsf(v.w)));
        a = fmaxf(a, __shfl_xor(a, 1));
        a = fmaxf(a, __shfl_xor(a, 2));
        a = fmaxf(a, __shfl_xor(a, 4));
        int se = shared_exp(a);
        float s = exp2i(se), inv = exp2i(-se);
        float q0, q1, q2, q3;
        qdq2(v.x, v.y, inv, s, q0, q1);
        qdq2(v.z, v.w, inv, s, q2, q3);
        tile[c4 * 4 + 0][row] = (u16)(__float_as_uint(q0) >> 16);
        tile[c4 * 4 + 1][row] = (u16)(__float_as_uint(q1) >> 16);
        tile[c4 * 4 + 2][row] = (u16)(__float_as_uint(q2) >> 16);
        tile[c4 * 4 + 3][row] = (u16)(__float_as_uint(q3) >> 16);
    }
    __syncthreads();
    #pragma unroll
    for (int p = 0; p < 4; ++p) {
        int lin = p * 256 + t;
        int n  = lin >> 4;
        int k4 = lin & 15;
        unsigned lo = tile[n][k4 * 4 + 0] | ((unsigned)tile[n][k4 * 4 + 1] << 16);
        unsigned hi = tile[n][k4 * 4 + 2] | ((unsigned)tile[n][k4 * 4 + 3] << 16);
        *(uint2*)(out + (size_t)(c0 + n) * R + r0 + k4 * 4) = make_uint2(lo, hi);
    }
}

// ---------- kernel 3: bf16 GEMM, C = A * B  with B stored transposed [N][K] ----------
// 128x128 tile, BK=32, 4 waves as 2x2 of 64x64, 16x16x32 bf16 MFMA.
// LDS layout XOR-swizzled: chunk c (16B) of row r lives at slot r*4 + (c ^ ((r>>1)&3)),
// making fragment ds_read_b128 conflict-free (each 8-lane phase covers all 32 banks).
__global__ __launch_bounds__(256) void gemm_bt(const u16* __restrict__ A,
                                               const u16* __restrict__ B,
                                               float* __restrict__ C) {
    const int K = 4096, N = 4096;
    __shared__ __align__(16) u16 As[128 * 32];
    __shared__ __align__(16) u16 Bs[128 * 32];
    int t = threadIdx.x;
    int m0 = blockIdx.y * 128, n0 = blockIdx.x * 128;
    int w = t >> 6, lane = t & 63;
    int wm = (w >> 1) * 64, wc = (w & 1) * 64;
    int lcol = lane & 15, lq = lane >> 4;
    int sw = (lq ^ ((lcol >> 1) & 3)) * 8;   // lane-constant read swizzle (elements)

    f32x4 acc[4][4];
    #pragma unroll
    for (int r = 0; r < 4; ++r)
        #pragma unroll
        for (int c = 0; c < 4; ++c) acc[r][c] = (f32x4){0.f, 0.f, 0.f, 0.f};

    // staging: lane t writes LDS slots t and 256+t (hardware-required contiguous);
    // slot s holds global chunk (row = s>>2, c = (s&3) ^ ((s>>3)&3))
    int s0 = t, s1 = 256 + t;
    int eo0 = s0 * 8, eo1 = s1 * 8;                      // LDS element offsets
    int ar0 = s0 >> 2, ac0 = ((s0 & 3) ^ ((s0 >> 3) & 3)) * 8;
    int ar1 = s1 >> 2, ac1 = ((s1 & 3) ^ ((s1 >> 3) & 3)) * 8;

    const u16* Ab = A + (size_t)m0 * K;
    const u16* Bb = B + (size_t)n0 * K;

    for (int k0 = 0; k0 < K; k0 += 32) {
        __builtin_amdgcn_global_load_lds((const AS1 unsigned*)(Ab + (size_t)ar0 * K + k0 + ac0),
                                         (AS3 unsigned*)&As[eo0], 16, 0, 0);
        __builtin_amdgcn_global_load_lds((const AS1 unsigned*)(Ab + (size_t)ar1 * K + k0 + ac1),
                                         (AS3 unsigned*)&As[eo1], 16, 0, 0);
        __builtin_amdgcn_global_load_lds((const AS1 unsigned*)(Bb + (size_t)ar0 * K + k0 + ac0),
                                         (AS3 unsigned*)&Bs[eo0], 16, 0, 0);
        __builtin_amdgcn_global_load_lds((const AS1 unsigned*)(Bb + (size_t)ar1 * K + k0 + ac1),
                                         (AS3 unsigned*)&Bs[eo1], 16, 0, 0);
        __syncthreads();

        bf16x8 af[4], bfv[4];
        #pragma unroll
        for (int r = 0; r < 4; ++r)
            af[r] = *(const bf16x8*)&As[(wm + r * 16 + lcol) * 32 + sw];
        #pragma unroll
        for (int c = 0; c < 4; ++c)
            bfv[c] = *(const bf16x8*)&Bs[(wc + c * 16 + lcol) * 32 + sw];

        #pragma unroll
        for (int r = 0; r < 4; ++r)
            #pragma unroll
            for (int c = 0; c < 4; ++c)
                acc[r][c] = __builtin_amdgcn_mfma_f32_16x16x32_bf16(af[r], bfv[c], acc[r][c], 0, 0, 0);
        __syncthreads();
    }

    // epilogue: C/D layout col = lane&15, row = (lane>>4)*4 + i
    #pragma unroll
    for (int r = 0; r < 4; ++r) {
        int gr = m0 + wm + r * 16 + lq * 4;
        #pragma unroll
        for (int c = 0; c < 4; ++c) {
            int gc = n0 + wc + c * 16 + lcol;
            #pragma unroll
            for (int i = 0; i < 4; ++i)
                C[(size_t)(gr + i) * N + gc] = acc[r][c][i];
        }
    }
}

// ---------- launch ----------
extern "C" void kernel_launch(void* const* d_in, const int* in_sizes, int n_in,
                              void* d_out, int out_size, void* d_ws, size_t ws_size,
                              hipStream_t stream) {
    const float* x  = (const float*)d_in[0];   // [4096, 4096]
    const float* m1 = (const float*)d_in[1];   // [4096, 4096]
    const float* m2 = (const float*)d_in[2];   // [4096, 4096]
    float* out = (float*)d_out;                // [4096, 4096] fp32

    const int M = 4096, K = 4096, N = 4096;
    const size_t MB = 1024 * 1024;
    char* ws = (char*)d_ws;
    u16*  xq   = (u16*)(ws + 0 * MB);    // 32 MB   qdq(x) bf16 [M][K]
    u16*  m1qT = (u16*)(ws + 32 * MB);   // 32 MB   qdq(mat1)^T bf16 [K][K]
    u16*  m2qT = (u16*)(ws + 64 * MB);   // 32 MB   qdq(mat2)^T bf16 [N][K]
    float* xh  = (float*)(ws + 96 * MB); // 64 MB   x_high fp32 [M][K]
    u16*  xrq  = (u16*)(ws + 0 * MB);    // reuse xq region (dead after GEMM1)

    dim3 b(256);
    qdq_rows<<<dim3((M * K) / 2048), b, 0, stream>>>(x, xq);
    qdq_transpose<<<dim3(K / 64, K / 64), b, 0, stream>>>(m1, m1qT, K, K);
    qdq_transpose<<<dim3(N / 64, K / 64), b, 0, stream>>>(m2, m2qT, K, N);
    gemm_bt<<<dim3(N / 128, M / 128), b, 0, stream>>>(xq, m1qT, xh);
    qdq_rows<<<dim3((M * K) / 2048), b, 0, stream>>>(xh, xrq);
    gemm_bt<<<dim3(N / 128, M / 128), b, 0, stream>>>(xrq, m2qT, out);
}

// Round 3
// 567.181 us; speedup vs baseline: 1.0998x; 1.0585x over previous
//
#include <hip/hip_runtime.h>
#include <hip/hip_bf16.h>
#include <cstdint>

typedef unsigned short u16;
typedef __bf16 bf16x8 __attribute__((ext_vector_type(8)));
typedef float f32x16 __attribute__((ext_vector_type(16)));
typedef float f32x2 __attribute__((ext_vector_type(2)));

#define AS1 __attribute__((address_space(1)))
#define AS3 __attribute__((address_space(3)))

// ---------- exact MX quant-dequant helpers (HW fp8 path) ----------

__device__ __forceinline__ int floor_log2(float x) {
    unsigned b = __float_as_uint(x);
    if (b < 0x00800000u) {                       // subnormal (rare)
        b = __float_as_uint(x * 16777216.0f);    // * 2^24 exact
        return (int)(b >> 23) - 151;
    }
    return (int)(b >> 23) - 127;
}

__device__ __forceinline__ float exp2i(int e) {
    if (e >= -126) return __uint_as_float((unsigned)(e + 127) << 23);
    return __uint_as_float(0x00400000u >> (-127 - e));
}

__device__ __forceinline__ int shared_exp(float amax) {
    float safe = (amax == 0.0f) ? 1.0f : amax;
    int se = floor_log2(safe) - 8;
    return se < -127 ? -127 : (se > 127 ? 127 : se);
}

// qdq two values with independent scales; exact e4m3fn RNE via HW cvt
__device__ __forceinline__ void qdq2s(float v0, float v1, float i0, float i1,
                                      float s0, float s1, float& o0, float& o1) {
    float y0 = fminf(fmaxf(v0 * i0, -448.0f), 448.0f);
    float y1 = fminf(fmaxf(v1 * i1, -448.0f), 448.0f);
    int pk = __builtin_amdgcn_cvt_pk_fp8_f32(y0, y1, 0, false);
    f32x2 f = __builtin_amdgcn_cvt_pk_f32_fp8(pk, false);
    o0 = f.x * s0;
    o1 = f.y * s1;
}

__device__ __forceinline__ unsigned pack_bf16(float a, float b) {
    return (__float_as_uint(a) >> 16) | (__float_as_uint(b) & 0xffff0000u);
}

// ---------- kernel 1: row-major qdq fp32 -> bf16 (blocks = 32 consecutive) ----------
__global__ void qdq_rows(const float* __restrict__ in, u16* __restrict__ out) {
    size_t t = (size_t)blockIdx.x * 256 + threadIdx.x;
    float4 v0 = ((const float4*)in)[t * 2];
    float4 v1 = ((const float4*)in)[t * 2 + 1];
    float a = fmaxf(fmaxf(fabsf(v0.x), fabsf(v0.y)), fmaxf(fabsf(v0.z), fabsf(v0.w)));
    a = fmaxf(a, fmaxf(fmaxf(fabsf(v1.x), fabsf(v1.y)), fmaxf(fabsf(v1.z), fabsf(v1.w))));
    a = fmaxf(a, __shfl_xor(a, 1));
    a = fmaxf(a, __shfl_xor(a, 2));
    int se = shared_exp(a);
    float s = exp2i(se), inv = exp2i(-se);
    float q0, q1, q2, q3, q4, q5, q6, q7;
    qdq2s(v0.x, v0.y, inv, inv, s, s, q0, q1);
    qdq2s(v0.z, v0.w, inv, inv, s, s, q2, q3);
    qdq2s(v1.x, v1.y, inv, inv, s, s, q4, q5);
    qdq2s(v1.z, v1.w, inv, inv, s, s, q6, q7);
    uint4 o;
    o.x = pack_bf16(q0, q1);
    o.y = pack_bf16(q2, q3);
    o.z = pack_bf16(q4, q5);
    o.w = pack_bf16(q6, q7);
    ((uint4*)out)[t] = o;
}

// ---------- kernel 2: qdq + transpose fp32 [R][C] -> bf16 [C][R] ----------
__global__ void qdq_transpose(const float* __restrict__ in, u16* __restrict__ out,
                              int R, int C) {
    __shared__ u16 tile[64][70];   // stride 70: write banks 3*c4 mod 32, all distinct
    int c0 = blockIdx.x * 64, r0 = blockIdx.y * 64;
    int t = threadIdx.x;
    #pragma unroll
    for (int p = 0; p < 4; ++p) {
        int lin = p * 256 + t;
        int row = lin >> 4;
        int c4  = lin & 15;
        float4 v = *(const float4*)(in + (size_t)(r0 + row) * C + c0 + c4 * 4);
        float a = fmaxf(fmaxf(fabsf(v.x), fabsf(v.y)), fmaxf(fabsf(v.z), fabsf(v.w)));
        a = fmaxf(a, __shfl_xor(a, 1));
        a = fmaxf(a, __shfl_xor(a, 2));
        a = fmaxf(a, __shfl_xor(a, 4));
        int se = shared_exp(a);
        float s = exp2i(se), inv = exp2i(-se);
        float q0, q1, q2, q3;
        qdq2s(v.x, v.y, inv, inv, s, s, q0, q1);
        qdq2s(v.z, v.w, inv, inv, s, s, q2, q3);
        tile[c4 * 4 + 0][row] = (u16)(__float_as_uint(q0) >> 16);
        tile[c4 * 4 + 1][row] = (u16)(__float_as_uint(q1) >> 16);
        tile[c4 * 4 + 2][row] = (u16)(__float_as_uint(q2) >> 16);
        tile[c4 * 4 + 3][row] = (u16)(__float_as_uint(q3) >> 16);
    }
    __syncthreads();
    #pragma unroll
    for (int p = 0; p < 4; ++p) {
        int lin = p * 256 + t;
        int n  = lin >> 4;
        int k4 = lin & 15;
        unsigned lo = *(const unsigned*)&tile[n][k4 * 4];       // 4B aligned: 140n+8k4
        unsigned hi = *(const unsigned*)&tile[n][k4 * 4 + 2];
        *(uint2*)(out + (size_t)(c0 + n) * R + r0 + k4 * 4) = make_uint2(lo, hi);
    }
}

// ---------- GEMM core: 128x128 tile, BK=32, 4 waves, 32x32x16 bf16 MFMA ----------
// LDS XOR-swizzled: 16B chunk p of row r holds global chunk p ^ ((r>>1)&3).
__device__ __forceinline__ void gemm_core(const u16* __restrict__ A,
                                          const u16* __restrict__ B,
                                          u16* As, u16* Bs,
                                          int m0, int n0, f32x16 acc[2][2]) {
    const int K = 4096;
    int t = threadIdx.x;
    int w = t >> 6, lane = t & 63;
    int wm = (w >> 1) * 64, wc = (w & 1) * 64;
    int l31 = lane & 31, lh = lane >> 5;

    #pragma unroll
    for (int rt = 0; rt < 2; ++rt)
        #pragma unroll
        for (int ct = 0; ct < 2; ++ct)
            acc[rt][ct] = (f32x16)0.f;

    int s0 = t, s1 = 256 + t;
    int eo0 = s0 * 8, eo1 = s1 * 8;
    int ar0 = s0 >> 2, ac0 = ((s0 & 3) ^ ((s0 >> 3) & 3)) * 8;
    int ar1 = s1 >> 2, ac1 = ((s1 & 3) ^ ((s1 >> 3) & 3)) * 8;

    const u16* Ab = A + (size_t)m0 * K;
    const u16* Bb = B + (size_t)n0 * K;

    // fragment LDS offsets (lane-constant parts)
    int arow[2], brow[2];
    #pragma unroll
    for (int i = 0; i < 2; ++i) { arow[i] = wm + i * 32 + l31; brow[i] = wc + i * 32 + l31; }

    for (int k0 = 0; k0 < K; k0 += 32) {
        __builtin_amdgcn_global_load_lds((const AS1 unsigned*)(Ab + (size_t)ar0 * K + k0 + ac0),
                                         (AS3 unsigned*)&As[eo0], 16, 0, 0);
        __builtin_amdgcn_global_load_lds((const AS1 unsigned*)(Ab + (size_t)ar1 * K + k0 + ac1),
                                         (AS3 unsigned*)&As[eo1], 16, 0, 0);
        __builtin_amdgcn_global_load_lds((const AS1 unsigned*)(Bb + (size_t)ar0 * K + k0 + ac0),
                                         (AS3 unsigned*)&Bs[eo0], 16, 0, 0);
        __builtin_amdgcn_global_load_lds((const AS1 unsigned*)(Bb + (size_t)ar1 * K + k0 + ac1),
                                         (AS3 unsigned*)&Bs[eo1], 16, 0, 0);
        __syncthreads();

        bf16x8 af[2][2], bfv[2][2];   // [tile][kstep]
        #pragma unroll
        for (int rt = 0; rt < 2; ++rt)
            #pragma unroll
            for (int ks = 0; ks < 2; ++ks) {
                int chunk = ks * 2 + lh;
                af[rt][ks]  = *(const bf16x8*)&As[arow[rt] * 32 + (chunk ^ ((arow[rt] >> 1) & 3)) * 8];
                bfv[rt][ks] = *(const bf16x8*)&Bs[brow[rt] * 32 + (chunk ^ ((brow[rt] >> 1) & 3)) * 8];
            }

        #pragma unroll
        for (int ks = 0; ks < 2; ++ks)
            #pragma unroll
            for (int rt = 0; rt < 2; ++rt)
                #pragma unroll
                for (int ct = 0; ct < 2; ++ct)
                    acc[rt][ct] = __builtin_amdgcn_mfma_f32_32x32x16_bf16(
                        af[rt][ks], bfv[ct][ks], acc[rt][ct], 0, 0, 0);
        __syncthreads();
    }
}

// GEMM1: C = A*B^T, output re-quantized to MX bf16 (blocks = 32 cols) in-register
__global__ __launch_bounds__(256) void gemm1_fused(const u16* __restrict__ A,
                                                   const u16* __restrict__ B,
                                                   u16* __restrict__ Cq) {
    const int N = 4096;
    __shared__ __align__(16) u16 As[128 * 32];
    __shared__ __align__(16) u16 Bs[128 * 32];
    int m0 = blockIdx.y * 128, n0 = blockIdx.x * 128;
    f32x16 acc[2][2];
    gemm_core(A, B, As, Bs, m0, n0, acc);

    int lane = threadIdx.x & 63, w = threadIdx.x >> 6;
    int wm = (w >> 1) * 64, wc = (w & 1) * 64;
    int l31 = lane & 31, lh = lane >> 5;

    // C/D layout: col = lane&31, row = (reg&3) + 8*(reg>>2) + 4*lh
    #pragma unroll
    for (int rt = 0; rt < 2; ++rt)
        #pragma unroll
        for (int ct = 0; ct < 2; ++ct) {
            float sc[16], iv[16];
            #pragma unroll
            for (int reg = 0; reg < 16; ++reg) {
                float a = fabsf(acc[rt][ct][reg]);
                a = fmaxf(a, __shfl_xor(a, 1));
                a = fmaxf(a, __shfl_xor(a, 2));
                a = fmaxf(a, __shfl_xor(a, 4));
                a = fmaxf(a, __shfl_xor(a, 8));
                a = fmaxf(a, __shfl_xor(a, 16));
                int se = shared_exp(a);
                sc[reg] = exp2i(se);
                iv[reg] = exp2i(-se);
            }
            int gc = n0 + wc + ct * 32 + l31;
            int gr_base = m0 + wm + rt * 32 + 4 * lh;
            #pragma unroll
            for (int reg = 0; reg < 16; reg += 2) {
                float q0, q1;
                qdq2s(acc[rt][ct][reg], acc[rt][ct][reg + 1],
                      iv[reg], iv[reg + 1], sc[reg], sc[reg + 1], q0, q1);
                int r0i = gr_base + (reg & 3) + 8 * (reg >> 2);
                int r1i = gr_base + ((reg + 1) & 3) + 8 * ((reg + 1) >> 2);
                Cq[(size_t)r0i * N + gc] = (u16)(__float_as_uint(q0) >> 16);
                Cq[(size_t)r1i * N + gc] = (u16)(__float_as_uint(q1) >> 16);
            }
        }
}

// GEMM2: C = A*B^T, plain fp32 output
__global__ __launch_bounds__(256) void gemm2(const u16* __restrict__ A,
                                             const u16* __restrict__ B,
                                             float* __restrict__ C) {
    const int N = 4096;
    __shared__ __align__(16) u16 As[128 * 32];
    __shared__ __align__(16) u16 Bs[128 * 32];
    int m0 = blockIdx.y * 128, n0 = blockIdx.x * 128;
    f32x16 acc[2][2];
    gemm_core(A, B, As, Bs, m0, n0, acc);

    int lane = threadIdx.x & 63, w = threadIdx.x >> 6;
    int wm = (w >> 1) * 64, wc = (w & 1) * 64;
    int l31 = lane & 31, lh = lane >> 5;

    #pragma unroll
    for (int rt = 0; rt < 2; ++rt)
        #pragma unroll
        for (int ct = 0; ct < 2; ++ct) {
            int gc = n0 + wc + ct * 32 + l31;
            int gr_base = m0 + wm + rt * 32 + 4 * lh;
            #pragma unroll
            for (int reg = 0; reg < 16; ++reg) {
                int gr = gr_base + (reg & 3) + 8 * (reg >> 2);
                C[(size_t)gr * N + gc] = acc[rt][ct][reg];
            }
        }
}

// ---------- launch ----------
extern "C" void kernel_launch(void* const* d_in, const int* in_sizes, int n_in,
                              void* d_out, int out_size, void* d_ws, size_t ws_size,
                              hipStream_t stream) {
    const float* x  = (const float*)d_in[0];
    const float* m1 = (const float*)d_in[1];
    const float* m2 = (const float*)d_in[2];
    float* out = (float*)d_out;

    const int M = 4096, K = 4096, N = 4096;
    const size_t MB = 1024 * 1024;
    char* ws = (char*)d_ws;
    u16* xq   = (u16*)(ws + 0 * MB);    // 32 MB  qdq(x) bf16 [M][K]
    u16* m1qT = (u16*)(ws + 32 * MB);   // 32 MB  qdq(mat1)^T bf16 [K][K]
    u16* m2qT = (u16*)(ws + 64 * MB);   // 32 MB  qdq(mat2)^T bf16 [N][K]
    u16* xrq  = (u16*)(ws + 96 * MB);   // 32 MB  qdq(x@m1) bf16 [M][K]

    dim3 b(256);
    qdq_rows<<<dim3((M * K) / 2048), b, 0, stream>>>(x, xq);
    qdq_transpose<<<dim3(K / 64, K / 64), b, 0, stream>>>(m1, m1qT, K, K);
    qdq_transpose<<<dim3(N / 64, K / 64), b, 0, stream>>>(m2, m2qT, K, N);
    gemm1_fused<<<dim3(N / 128, M / 128), b, 0, stream>>>(xq, m1qT, xrq);
    gemm2<<<dim3(N / 128, M / 128), b, 0, stream>>>(xrq, m2qT, out);
}

// Round 4
// 557.065 us; speedup vs baseline: 1.1198x; 1.0182x over previous
//
#include <hip/hip_runtime.h>
#include <hip/hip_bf16.h>
#include <cstdint>

typedef unsigned short u16;
typedef __bf16 bf16x8 __attribute__((ext_vector_type(8)));
typedef float f32x16 __attribute__((ext_vector_type(16)));
typedef float f32x2 __attribute__((ext_vector_type(2)));

#define AS1 __attribute__((address_space(1)))
#define AS3 __attribute__((address_space(3)))

// ---------- exact MX quant-dequant helpers (HW fp8 path) ----------

__device__ __forceinline__ int floor_log2(float x) {
    unsigned b = __float_as_uint(x);
    if (b < 0x00800000u) {                       // subnormal (rare)
        b = __float_as_uint(x * 16777216.0f);    // * 2^24 exact
        return (int)(b >> 23) - 151;
    }
    return (int)(b >> 23) - 127;
}

__device__ __forceinline__ float exp2i(int e) {
    if (e >= -126) return __uint_as_float((unsigned)(e + 127) << 23);
    return __uint_as_float(0x00400000u >> (-127 - e));
}

__device__ __forceinline__ int shared_exp(float amax) {
    float safe = (amax == 0.0f) ? 1.0f : amax;
    int se = floor_log2(safe) - 8;
    return se < -127 ? -127 : (se > 127 ? 127 : se);
}

// qdq two values with independent scales; exact e4m3fn RNE via HW cvt
__device__ __forceinline__ void qdq2s(float v0, float v1, float i0, float i1,
                                      float s0, float s1, float& o0, float& o1) {
    float y0 = fminf(fmaxf(v0 * i0, -448.0f), 448.0f);
    float y1 = fminf(fmaxf(v1 * i1, -448.0f), 448.0f);
    int pk = __builtin_amdgcn_cvt_pk_fp8_f32(y0, y1, 0, false);
    f32x2 f = __builtin_amdgcn_cvt_pk_f32_fp8(pk, false);
    o0 = f.x * s0;
    o1 = f.y * s1;
}

__device__ __forceinline__ unsigned pack_bf16(float a, float b) {
    return (__float_as_uint(a) >> 16) | (__float_as_uint(b) & 0xffff0000u);
}

// ---------- kernel 1: row-major qdq fp32 -> bf16 (blocks = 32 consecutive) ----------
__global__ void qdq_rows(const float* __restrict__ in, u16* __restrict__ out) {
    size_t t = (size_t)blockIdx.x * 256 + threadIdx.x;
    float4 v0 = ((const float4*)in)[t * 2];
    float4 v1 = ((const float4*)in)[t * 2 + 1];
    float a = fmaxf(fmaxf(fabsf(v0.x), fabsf(v0.y)), fmaxf(fabsf(v0.z), fabsf(v0.w)));
    a = fmaxf(a, fmaxf(fmaxf(fabsf(v1.x), fabsf(v1.y)), fmaxf(fabsf(v1.z), fabsf(v1.w))));
    a = fmaxf(a, __shfl_xor(a, 1));
    a = fmaxf(a, __shfl_xor(a, 2));
    int se = shared_exp(a);
    float s = exp2i(se), inv = exp2i(-se);
    float q0, q1, q2, q3, q4, q5, q6, q7;
    qdq2s(v0.x, v0.y, inv, inv, s, s, q0, q1);
    qdq2s(v0.z, v0.w, inv, inv, s, s, q2, q3);
    qdq2s(v1.x, v1.y, inv, inv, s, s, q4, q5);
    qdq2s(v1.z, v1.w, inv, inv, s, s, q6, q7);
    uint4 o;
    o.x = pack_bf16(q0, q1);
    o.y = pack_bf16(q2, q3);
    o.z = pack_bf16(q4, q5);
    o.w = pack_bf16(q6, q7);
    ((uint4*)out)[t] = o;
}

// ---------- kernel 2: qdq + transpose fp32 [R][C] -> bf16 [C][R] ----------
__global__ void qdq_transpose(const float* __restrict__ in, u16* __restrict__ out,
                              int R, int C) {
    __shared__ u16 tile[64][70];   // stride 70: write banks 3*c4 mod 32, all distinct
    int c0 = blockIdx.x * 64, r0 = blockIdx.y * 64;
    int t = threadIdx.x;
    #pragma unroll
    for (int p = 0; p < 4; ++p) {
        int lin = p * 256 + t;
        int row = lin >> 4;
        int c4  = lin & 15;
        float4 v = *(const float4*)(in + (size_t)(r0 + row) * C + c0 + c4 * 4);
        float a = fmaxf(fmaxf(fabsf(v.x), fabsf(v.y)), fmaxf(fabsf(v.z), fabsf(v.w)));
        a = fmaxf(a, __shfl_xor(a, 1));
        a = fmaxf(a, __shfl_xor(a, 2));
        a = fmaxf(a, __shfl_xor(a, 4));
        int se = shared_exp(a);
        float s = exp2i(se), inv = exp2i(-se);
        float q0, q1, q2, q3;
        qdq2s(v.x, v.y, inv, inv, s, s, q0, q1);
        qdq2s(v.z, v.w, inv, inv, s, s, q2, q3);
        tile[c4 * 4 + 0][row] = (u16)(__float_as_uint(q0) >> 16);
        tile[c4 * 4 + 1][row] = (u16)(__float_as_uint(q1) >> 16);
        tile[c4 * 4 + 2][row] = (u16)(__float_as_uint(q2) >> 16);
        tile[c4 * 4 + 3][row] = (u16)(__float_as_uint(q3) >> 16);
    }
    __syncthreads();
    #pragma unroll
    for (int p = 0; p < 4; ++p) {
        int lin = p * 256 + t;
        int n  = lin >> 4;
        int k4 = lin & 15;
        unsigned lo = *(const unsigned*)&tile[n][k4 * 4];
        unsigned hi = *(const unsigned*)&tile[n][k4 * 4 + 2];
        *(uint2*)(out + (size_t)(c0 + n) * R + r0 + k4 * 4) = make_uint2(lo, hi);
    }
}

// ---------- GEMM core: 128x128 tile, BK=32, 4 waves, 32x32x16 bf16 MFMA ----------
// LDS XOR-swizzle f(r) = ((r>>1)^(r>>3))&3: 16B chunk c of row r stored at slot c^f(r).
// f varies over row bits {1,2} (consecutive-lane phases) AND bits {3,4} (stride-8
// phases) -> fragment ds_read_b128 is <=2-way in either HW phase grouping.
__device__ __forceinline__ void gemm_core(const u16* __restrict__ A,
                                          const u16* __restrict__ B,
                                          u16* As, u16* Bs,
                                          int m0, int n0, f32x16 acc[2][2]) {
    const int K = 4096;
    int t = threadIdx.x;
    int w = t >> 6, lane = t & 63;
    int wm = (w >> 1) * 64, wc = (w & 1) * 64;
    int l31 = lane & 31, lh = lane >> 5;

    #pragma unroll
    for (int rt = 0; rt < 2; ++rt)
        #pragma unroll
        for (int ct = 0; ct < 2; ++ct)
            acc[rt][ct] = (f32x16)0.f;

    // staging: lane t fills LDS slots t and 256+t; slot s holds global chunk
    // (row = s>>2, c = (s&3) ^ f(row)) with f(row) = ((row>>1)^(row>>3))&3
    int s0 = t, s1 = 256 + t;
    int eo0 = s0 * 8, eo1 = s1 * 8;
    int r0s = s0 >> 2, r1s = s1 >> 2;
    int ar0 = r0s, ac0 = ((s0 & 3) ^ (((r0s >> 1) ^ (r0s >> 3)) & 3)) * 8;
    int ar1 = r1s, ac1 = ((s1 & 3) ^ (((r1s >> 1) ^ (r1s >> 3)) & 3)) * 8;

    const u16* Ab = A + (size_t)m0 * K;
    const u16* Bb = B + (size_t)n0 * K;

    // reader: rows are base + l31 (base mult of 32) -> f depends only on l31
    int fr = ((l31 >> 1) ^ (l31 >> 3)) & 3;
    int arow[2], brow[2];
    #pragma unroll
    for (int i = 0; i < 2; ++i) { arow[i] = wm + i * 32 + l31; brow[i] = wc + i * 32 + l31; }

    for (int k0 = 0; k0 < K; k0 += 32) {
        __builtin_amdgcn_global_load_lds((const AS1 unsigned*)(Ab + (size_t)ar0 * K + k0 + ac0),
                                         (AS3 unsigned*)&As[eo0], 16, 0, 0);
        __builtin_amdgcn_global_load_lds((const AS1 unsigned*)(Ab + (size_t)ar1 * K + k0 + ac1),
                                         (AS3 unsigned*)&As[eo1], 16, 0, 0);
        __builtin_amdgcn_global_load_lds((const AS1 unsigned*)(Bb + (size_t)ar0 * K + k0 + ac0),
                                         (AS3 unsigned*)&Bs[eo0], 16, 0, 0);
        __builtin_amdgcn_global_load_lds((const AS1 unsigned*)(Bb + (size_t)ar1 * K + k0 + ac1),
                                         (AS3 unsigned*)&Bs[eo1], 16, 0, 0);
        __syncthreads();

        bf16x8 af[2][2], bfv[2][2];   // [tile][kstep]
        #pragma unroll
        for (int rt = 0; rt < 2; ++rt)
            #pragma unroll
            for (int ks = 0; ks < 2; ++ks) {
                int slot = (ks * 2 + lh) ^ fr;
                af[rt][ks]  = *(const bf16x8*)&As[arow[rt] * 32 + slot * 8];
                bfv[rt][ks] = *(const bf16x8*)&Bs[brow[rt] * 32 + slot * 8];
            }

        #pragma unroll
        for (int ks = 0; ks < 2; ++ks)
            #pragma unroll
            for (int rt = 0; rt < 2; ++rt)
                #pragma unroll
                for (int ct = 0; ct < 2; ++ct)
                    acc[rt][ct] = __builtin_amdgcn_mfma_f32_32x32x16_bf16(
                        af[rt][ks], bfv[ct][ks], acc[rt][ct], 0, 0, 0);
        __syncthreads();
    }
}

// GEMM1: C = A*B^T, output re-quantized to MX bf16 (blocks = 32 cols) in-register
__global__ __launch_bounds__(256) void gemm1_fused(const u16* __restrict__ A,
                                                   const u16* __restrict__ B,
                                                   u16* __restrict__ Cq) {
    const int N = 4096;
    __shared__ __align__(16) u16 As[128 * 32];
    __shared__ __align__(16) u16 Bs[128 * 32];
    int m0 = blockIdx.y * 128, n0 = blockIdx.x * 128;
    f32x16 acc[2][2];
    gemm_core(A, B, As, Bs, m0, n0, acc);

    int lane = threadIdx.x & 63, w = threadIdx.x >> 6;
    int wm = (w >> 1) * 64, wc = (w & 1) * 64;
    int l31 = lane & 31, lh = lane >> 5;

    // C/D layout: col = lane&31, row = (reg&3) + 8*(reg>>2) + 4*lh
    #pragma unroll
    for (int rt = 0; rt < 2; ++rt)
        #pragma unroll
        for (int ct = 0; ct < 2; ++ct) {
            float sc[16], iv[16];
            #pragma unroll
            for (int reg = 0; reg < 16; ++reg) {
                float a = fabsf(acc[rt][ct][reg]);
                a = fmaxf(a, __shfl_xor(a, 1));
                a = fmaxf(a, __shfl_xor(a, 2));
                a = fmaxf(a, __shfl_xor(a, 4));
                a = fmaxf(a, __shfl_xor(a, 8));
                a = fmaxf(a, __shfl_xor(a, 16));
                int se = shared_exp(a);
                sc[reg] = exp2i(se);
                iv[reg] = exp2i(-se);
            }
            int gc = n0 + wc + ct * 32 + l31;
            int gr_base = m0 + wm + rt * 32 + 4 * lh;
            #pragma unroll
            for (int reg = 0; reg < 16; reg += 2) {
                float q0, q1;
                qdq2s(acc[rt][ct][reg], acc[rt][ct][reg + 1],
                      iv[reg], iv[reg + 1], sc[reg], sc[reg + 1], q0, q1);
                int r0i = gr_base + (reg & 3) + 8 * (reg >> 2);
                int r1i = gr_base + ((reg + 1) & 3) + 8 * ((reg + 1) >> 2);
                Cq[(size_t)r0i * N + gc] = (u16)(__float_as_uint(q0) >> 16);
                Cq[(size_t)r1i * N + gc] = (u16)(__float_as_uint(q1) >> 16);
            }
        }
}

// GEMM2: C = A*B^T, plain fp32 output
__global__ __launch_bounds__(256) void gemm2(const u16* __restrict__ A,
                                             const u16* __restrict__ B,
                                             float* __restrict__ C) {
    const int N = 4096;
    __shared__ __align__(16) u16 As[128 * 32];
    __shared__ __align__(16) u16 Bs[128 * 32];
    int m0 = blockIdx.y * 128, n0 = blockIdx.x * 128;
    f32x16 acc[2][2];
    gemm_core(A, B, As, Bs, m0, n0, acc);

    int lane = threadIdx.x & 63, w = threadIdx.x >> 6;
    int wm = (w >> 1) * 64, wc = (w & 1) * 64;
    int l31 = lane & 31, lh = lane >> 5;

    #pragma unroll
    for (int rt = 0; rt < 2; ++rt)
        #pragma unroll
        for (int ct = 0; ct < 2; ++ct) {
            int gc = n0 + wc + ct * 32 + l31;
            int gr_base = m0 + wm + rt * 32 + 4 * lh;
            #pragma unroll
            for (int reg = 0; reg < 16; ++reg) {
                int gr = gr_base + (reg & 3) + 8 * (reg >> 2);
                C[(size_t)gr * N + gc] = acc[rt][ct][reg];
            }
        }
}

// ---------- launch ----------
extern "C" void kernel_launch(void* const* d_in, const int* in_sizes, int n_in,
                              void* d_out, int out_size, void* d_ws, size_t ws_size,
                              hipStream_t stream) {
    const float* x  = (const float*)d_in[0];
    const float* m1 = (const float*)d_in[1];
    const float* m2 = (const float*)d_in[2];
    float* out = (float*)d_out;

    const int M = 4096, K = 4096, N = 4096;
    const size_t MB = 1024 * 1024;
    char* ws = (char*)d_ws;
    u16* xq   = (u16*)(ws + 0 * MB);    // 32 MB  qdq(x) bf16 [M][K]
    u16* m1qT = (u16*)(ws + 32 * MB);   // 32 MB  qdq(mat1)^T bf16 [K][K]
    u16* m2qT = (u16*)(ws + 64 * MB);   // 32 MB  qdq(mat2)^T bf16 [N][K]
    u16* xrq  = (u16*)(ws + 96 * MB);   // 32 MB  qdq(x@m1) bf16 [M][K]

    dim3 b(256);
    qdq_rows<<<dim3((M * K) / 2048), b, 0, stream>>>(x, xq);
    qdq_transpose<<<dim3(K / 64, K / 64), b, 0, stream>>>(m1, m1qT, K, K);
    qdq_transpose<<<dim3(N / 64, K / 64), b, 0, stream>>>(m2, m2qT, K, N);
    gemm1_fused<<<dim3(N / 128, M / 128), b, 0, stream>>>(xq, m1qT, xrq);
    gemm2<<<dim3(N / 128, M / 128), b, 0, stream>>>(xrq, m2qT, out);
}